// Round 1
// baseline (319.368 us; speedup 1.0000x reference)
//
#include <hip/hip_runtime.h>
#include <hip/hip_bf16.h>
#include <stdint.h>

typedef unsigned short u16;
typedef __bf16 bf16x8 __attribute__((ext_vector_type(8)));
typedef float f32x4 __attribute__((ext_vector_type(4)));

#define D_MODEL 1024
#define SEQ     2048
#define NB      2
#define NH      16
#define HD      64
#define M_TOT   (NB*SEQ)        // 4096
#define ATT_SCALE 0.125f        // 1/sqrt(64)

__device__ __forceinline__ u16 f2bf(float f) {
  union { __bf16 b; u16 u; } cv; cv.b = (__bf16)f; return cv.u;
}

// async global->LDS, 16B per lane. lds_dst must be wave-uniform (HW adds lane*16).
__device__ __forceinline__ void async_copy16(void* lds_dst, const void* gsrc) {
  __builtin_amdgcn_global_load_lds(
      (const __attribute__((address_space(1))) unsigned int*)gsrc,
      (__attribute__((address_space(3))) unsigned int*)lds_dst, 16, 0, 0);
}

// ---------------- f32 -> bf16 convert (float4 per thread) ----------------
__global__ void cvt_f32_bf16(const float* __restrict__ in, u16* __restrict__ out, int n4) {
  int i = blockIdx.x * blockDim.x + threadIdx.x;
  if (i >= n4) return;
  float4 v = reinterpret_cast<const float4*>(in)[i];
  ushort4 o;
  o.x = f2bf(v.x); o.y = f2bf(v.y); o.z = f2bf(v.z); o.w = f2bf(v.w);
  reinterpret_cast<ushort4*>(out)[i] = o;
}

// ---------------- GEMM: C = A @ Bt^T + bias ----------------
// A [M][K] bf16 row-major, Bt [N][K] bf16 row-major (i.e. torch Linear weight).
// 128x128 tile, BK=32, 4 waves (2x2), each wave 64x64 via 4x4 mfma_16x16x32_bf16.
// LDS swizzle: 16B slot s of row r holds k-chunk (s ^ ((r>>1)&3)); staging
// pre-swizzles the GLOBAL source so global_load_lds dest stays linear (m201 rule).
template<int F32OUT>
__global__ __launch_bounds__(256, 3)
void gemm_bt(const u16* __restrict__ A,
             const u16* __restrict__ B0, const u16* __restrict__ B1, const u16* __restrict__ B2,
             const float* __restrict__ bias0, const float* __restrict__ bias1, const float* __restrict__ bias2,
             void* __restrict__ C0, void* __restrict__ C1, void* __restrict__ C2,
             int M, int N, int K)
{
  (void)M;
  const int z = blockIdx.z;
  const u16* Bt = (z == 0) ? B0 : ((z == 1) ? B1 : B2);
  const float* bias = (z == 0) ? bias0 : ((z == 1) ? bias1 : bias2);
  void* Cout = (z == 0) ? C0 : ((z == 1) ? C1 : C2);

  __shared__ u16 lds_a[2][128*32];
  __shared__ u16 lds_b[2][128*32];

  const int tid = threadIdx.x;
  const int w = tid >> 6, lane = tid & 63;
  const int l15 = lane & 15, lhi = lane >> 4;
  const int m0 = blockIdx.y * 128, n0 = blockIdx.x * 128;
  const int wm = w >> 1, wn = w & 1;

  f32x4 acc[4][4] = {};

  auto stage = [&](int buf, int kt) {
    const int k0 = kt * 32;
    #pragma unroll
    for (int i = 0; i < 2; ++i) {
      const int base = (w*2 + i) * 1024;          // byte offset of this 1KB wave-chunk
      const int pos  = base + (lane << 4);        // this lane's byte pos in tile
      const int row  = pos >> 6;                  // 64B per row (BK=32 bf16)
      const int slot = (pos >> 4) & 3;
      const int ss   = slot ^ ((row >> 1) & 3);   // inverse-swizzled global source
      async_copy16((char*)lds_a[buf] + base,
                   (const char*)(A  + (size_t)(m0 + row) * K + k0 + ss*8));
      async_copy16((char*)lds_b[buf] + base,
                   (const char*)(Bt + (size_t)(n0 + row) * K + k0 + ss*8));
    }
  };

  auto compute = [&](int buf) {
    bf16x8 af[4], bf[4];
    #pragma unroll
    for (int mi = 0; mi < 4; ++mi) {
      const int row = wm*64 + mi*16 + l15;
      const int s   = lhi ^ ((row >> 1) & 3);
      af[mi] = *reinterpret_cast<const bf16x8*>((const char*)lds_a[buf] + row*64 + s*16);
    }
    #pragma unroll
    for (int ni = 0; ni < 4; ++ni) {
      const int row = wn*64 + ni*16 + l15;
      const int s   = lhi ^ ((row >> 1) & 3);
      bf[ni] = *reinterpret_cast<const bf16x8*>((const char*)lds_b[buf] + row*64 + s*16);
    }
    #pragma unroll
    for (int mi = 0; mi < 4; ++mi)
      #pragma unroll
      for (int ni = 0; ni < 4; ++ni)
        acc[mi][ni] = __builtin_amdgcn_mfma_f32_16x16x32_bf16(af[mi], bf[ni], acc[mi][ni], 0, 0, 0);
  };

  stage(0, 0);
  __syncthreads();
  const int nk = K >> 5;
  for (int kt = 0; kt < nk; ++kt) {
    if (kt + 1 < nk) stage((kt + 1) & 1, kt + 1);
    compute(kt & 1);
    __syncthreads();
  }

  // epilogue: C/D layout col=lane&15, row=(lane>>4)*4+reg
  #pragma unroll
  for (int mi = 0; mi < 4; ++mi) {
    const int rowb = m0 + wm*64 + mi*16 + (lhi << 2);
    #pragma unroll
    for (int ni = 0; ni < 4; ++ni) {
      const int col = n0 + wn*64 + ni*16 + l15;
      const float bb = bias[col];
      #pragma unroll
      for (int r = 0; r < 4; ++r) {
        const float v = acc[mi][ni][r] + bb;
        if (F32OUT)
          reinterpret_cast<float*>(Cout)[(size_t)(rowb + r) * N + col] = v;
        else
          reinterpret_cast<u16*>(Cout)[(size_t)(rowb + r) * N + col] = f2bf(v);
      }
    }
  }
}

// ---------------- fused flash attention ----------------
// grid: (SEQ/64, NB*NH). 256 threads = 4 waves; wave w owns q rows [q0+16w, q0+16w+16).
// KV tiles of 64. K frags read directly from global (L2-resident).
// V staged transposed+swizzled in LDS; P round-trips LDS (swizzled) to reach MFMA-A layout.
__global__ __launch_bounds__(256, 2)
void attn_kernel(const u16* __restrict__ Qb, const u16* __restrict__ Kb,
                 const u16* __restrict__ Vb, u16* __restrict__ Ob)
{
  __shared__ u16 vt[64*64];          // V^T tile [d][key], XOR-swizzled
  __shared__ u16 p_lds[4][16*64];    // per-wave P [q][key], XOR-swizzled

  const int tid = threadIdx.x;
  const int w = tid >> 6, lane = tid & 63;
  const int l15 = lane & 15, lhi = lane >> 4;
  const int bh = blockIdx.y;
  const int b = bh >> 4, h = bh & 15;
  const int q0 = blockIdx.x * 64;

  // Q fragments (k = head dim, 2 k-steps of 32), hoisted out of KV loop
  bf16x8 aq[2];
  {
    const u16* qp = Qb + (size_t)(b*SEQ + q0 + w*16 + l15) * D_MODEL + h*HD + lhi*8;
    aq[0] = *reinterpret_cast<const bf16x8*>(qp);
    aq[1] = *reinterpret_cast<const bf16x8*>(qp + 32);
  }

  float mrun[4] = {-INFINITY, -INFINITY, -INFINITY, -INFINITY};
  float lrun[4] = {0.f, 0.f, 0.f, 0.f};
  f32x4 o[4] = {};

  for (int kv0 = 0; kv0 < SEQ; kv0 += 64) {
    __syncthreads();   // previous tile's PV reads of vt are done
    // stage V^T (cooperative): 512 chunks of 8 contiguous d-elems
    #pragma unroll
    for (int c = 0; c < 2; ++c) {
      const int idx = c*256 + tid;
      const int key = idx >> 3, dblk = (idx & 7) * 8;
      const u16* vsrc = Vb + (size_t)(b*SEQ + kv0 + key) * D_MODEL + h*HD + dblk;
      union { uint4 u; u16 s[8]; } val;
      val.u = *reinterpret_cast<const uint4*>(vsrc);
      #pragma unroll
      for (int j = 0; j < 8; ++j) {
        const int d = dblk + j;
        int byte = (d << 7) + (key << 1);
        byte ^= (d & 7) << 4;
        *reinterpret_cast<u16*>(reinterpret_cast<char*>(vt) + byte) = val.s[j];
      }
    }
    __syncthreads();

    // scores S = Q K^T * scale  (per wave: 16q x 64key)
    f32x4 s[4] = {};
    #pragma unroll
    for (int ks = 0; ks < 2; ++ks) {
      #pragma unroll
      for (int nt = 0; nt < 4; ++nt) {
        const u16* kp = Kb + (size_t)(b*SEQ + kv0 + nt*16 + l15) * D_MODEL + h*HD + ks*32 + lhi*8;
        bf16x8 bk = *reinterpret_cast<const bf16x8*>(kp);
        s[nt] = __builtin_amdgcn_mfma_f32_16x16x32_bf16(aq[ks], bk, s[nt], 0, 0, 0);
      }
    }
    #pragma unroll
    for (int nt = 0; nt < 4; ++nt)
      #pragma unroll
      for (int r = 0; r < 4; ++r) s[nt][r] *= ATT_SCALE;

    // online softmax stats; row r of lane lives at q=(lhi*4+r), key=nt*16+l15
    float mnew[4], rs[4];
    #pragma unroll
    for (int r = 0; r < 4; ++r) {
      float v = fmaxf(fmaxf(s[0][r], s[1][r]), fmaxf(s[2][r], s[3][r]));
      v = fmaxf(v, __shfl_xor(v, 1));
      v = fmaxf(v, __shfl_xor(v, 2));
      v = fmaxf(v, __shfl_xor(v, 4));
      v = fmaxf(v, __shfl_xor(v, 8));
      mnew[r] = fmaxf(mrun[r], v);
      rs[r] = 0.f;
    }
    #pragma unroll
    for (int nt = 0; nt < 4; ++nt)
      #pragma unroll
      for (int r = 0; r < 4; ++r) {
        const float e = __expf(s[nt][r] - mnew[r]);
        s[nt][r] = e;
        rs[r] += e;
      }
    #pragma unroll
    for (int r = 0; r < 4; ++r) {
      rs[r] += __shfl_xor(rs[r], 1);
      rs[r] += __shfl_xor(rs[r], 2);
      rs[r] += __shfl_xor(rs[r], 4);
      rs[r] += __shfl_xor(rs[r], 8);
      const float a = __expf(mrun[r] - mnew[r]);   // 0 on first tile (-inf)
      lrun[r] = lrun[r] * a + rs[r];
      mrun[r] = mnew[r];
      #pragma unroll
      for (int nt = 0; nt < 4; ++nt) o[nt][r] *= a;
    }

    // P -> LDS (bf16, swizzled), per-wave private region
    #pragma unroll
    for (int nt = 0; nt < 4; ++nt)
      #pragma unroll
      for (int r = 0; r < 4; ++r) {
        const int q = lhi*4 + r, key = nt*16 + l15;
        int byte = (q << 7) + (key << 1);
        byte ^= (q & 7) << 4;
        *reinterpret_cast<u16*>(reinterpret_cast<char*>(p_lds[w]) + byte) = f2bf(s[nt][r]);
      }
    // (wave-private LDS: compiler inserts lgkmcnt ordering; no barrier needed)

    // O += P @ V   (A = P[16q x 64key], B = V^T via vt)
    #pragma unroll
    for (int ks = 0; ks < 2; ++ks) {
      int byteA = (l15 << 7) + ks*64 + (lhi << 4);
      byteA ^= (l15 & 7) << 4;
      bf16x8 ap = *reinterpret_cast<const bf16x8*>(reinterpret_cast<const char*>(p_lds[w]) + byteA);
      #pragma unroll
      for (int nt = 0; nt < 4; ++nt) {
        const int d = nt*16 + l15;
        int byteB = (d << 7) + ks*64 + (lhi << 4);
        byteB ^= (d & 7) << 4;
        bf16x8 bv = *reinterpret_cast<const bf16x8*>(reinterpret_cast<const char*>(vt) + byteB);
        o[nt] = __builtin_amdgcn_mfma_f32_16x16x32_bf16(ap, bv, o[nt], 0, 0, 0);
      }
    }
  }

  // epilogue: divide by l, write [B,S,D] bf16
  #pragma unroll
  for (int nt = 0; nt < 4; ++nt)
    #pragma unroll
    for (int r = 0; r < 4; ++r) {
      const int row = q0 + w*16 + lhi*4 + r;
      const int col = h*HD + nt*16 + l15;
      const float v = o[nt][r] / lrun[r];
      Ob[(size_t)(b*SEQ + row) * D_MODEL + col] = f2bf(v);
    }
}

// ---------------- launcher ----------------
extern "C" void kernel_launch(void* const* d_in, const int* in_sizes, int n_in,
                              void* d_out, int out_size, void* d_ws, size_t ws_size,
                              hipStream_t stream)
{
  (void)in_sizes; (void)n_in; (void)out_size;
  const float* Z  = (const float*)d_in[0];
  const float* Wq = (const float*)d_in[1];
  const float* bq = (const float*)d_in[2];
  const float* Wk = (const float*)d_in[3];
  const float* bk = (const float*)d_in[4];
  const float* Wv = (const float*)d_in[5];
  const float* bv = (const float*)d_in[6];
  const float* Wo = (const float*)d_in[7];
  const float* bo = (const float*)d_in[8];
  float* out = (float*)d_out;

  // ws layout (bf16 elements): Zb | Wqb Wkb Wvb Wob | Qb Kb Vb | attn
  const size_t needed = (size_t)(M_TOT*D_MODEL)*2*5 + (size_t)(D_MODEL*D_MODEL)*2*4;
  if (ws_size < needed) return;   // leave d_out poisoned -> clear failure signal

  u16* Zb  = (u16*)d_ws;
  u16* Wqb = Zb  + (size_t)M_TOT*D_MODEL;
  u16* Wkb = Wqb + (size_t)D_MODEL*D_MODEL;
  u16* Wvb = Wkb + (size_t)D_MODEL*D_MODEL;
  u16* Wob = Wvb + (size_t)D_MODEL*D_MODEL;
  u16* Qb  = Wob + (size_t)D_MODEL*D_MODEL;
  u16* Kb  = Qb  + (size_t)M_TOT*D_MODEL;
  u16* Vb  = Kb  + (size_t)M_TOT*D_MODEL;
  u16* Ab  = Vb  + (size_t)M_TOT*D_MODEL;

  cvt_f32_bf16<<<dim3(M_TOT*D_MODEL/4/256), 256, 0, stream>>>(Z,  Zb,  M_TOT*D_MODEL/4);
  cvt_f32_bf16<<<dim3(D_MODEL*D_MODEL/4/256), 256, 0, stream>>>(Wq, Wqb, D_MODEL*D_MODEL/4);
  cvt_f32_bf16<<<dim3(D_MODEL*D_MODEL/4/256), 256, 0, stream>>>(Wk, Wkb, D_MODEL*D_MODEL/4);
  cvt_f32_bf16<<<dim3(D_MODEL*D_MODEL/4/256), 256, 0, stream>>>(Wv, Wvb, D_MODEL*D_MODEL/4);
  cvt_f32_bf16<<<dim3(D_MODEL*D_MODEL/4/256), 256, 0, stream>>>(Wo, Wob, D_MODEL*D_MODEL/4);

  // QKV projections, fused over gridDim.z
  dim3 gproj(D_MODEL/128, M_TOT/128, 3);
  gemm_bt<0><<<gproj, 256, 0, stream>>>(Zb, Wqb, Wkb, Wvb, bq, bk, bv,
                                        (void*)Qb, (void*)Kb, (void*)Vb,
                                        M_TOT, D_MODEL, D_MODEL);

  dim3 gattn(SEQ/64, NB*NH);
  attn_kernel<<<gattn, 256, 0, stream>>>(Qb, Kb, Vb, Ab);

  // output projection -> fp32 d_out
  dim3 gout(D_MODEL/128, M_TOT/128, 1);
  gemm_bt<1><<<gout, 256, 0, stream>>>(Ab, Wob, Wob, Wob, bo, bo, bo,
                                       (void*)out, (void*)out, (void*)out,
                                       M_TOT, D_MODEL, D_MODEL);
}

// Round 3
// 240.557 us; speedup vs baseline: 1.3276x; 1.3276x over previous
//
#include <hip/hip_runtime.h>
#include <hip/hip_bf16.h>
#include <stdint.h>

typedef unsigned short u16;
typedef __bf16 bf16x8 __attribute__((ext_vector_type(8)));
typedef float f32x4 __attribute__((ext_vector_type(4)));
typedef float f32x16 __attribute__((ext_vector_type(16)));

#define D_MODEL 1024
#define SEQ     2048
#define NB      2
#define NH      16
#define HD      64
#define M_TOT   (NB*SEQ)        // 4096
#define ATT_SCALE 0.125f        // 1/sqrt(64)

__device__ __forceinline__ u16 f2bf(float f) {
  union { __bf16 b; u16 u; } cv; cv.b = (__bf16)f; return cv.u;
}

// async global->LDS, 16B per lane. lds_dst must be wave-uniform (HW adds lane*16).
__device__ __forceinline__ void async_copy16(void* lds_dst, const void* gsrc) {
  __builtin_amdgcn_global_load_lds(
      (const __attribute__((address_space(1))) unsigned int*)gsrc,
      (__attribute__((address_space(3))) unsigned int*)lds_dst, 16, 0, 0);
}

// ---------------- fused f32 -> bf16 convert for Z + 4 weights ----------------
__global__ void cvt_all(const float* __restrict__ Z,  const float* __restrict__ Wq,
                        const float* __restrict__ Wk, const float* __restrict__ Wv,
                        const float* __restrict__ Wo,
                        u16* __restrict__ Zb,  u16* __restrict__ Wqb,
                        u16* __restrict__ Wkb, u16* __restrict__ Wvb,
                        u16* __restrict__ Wob)
{
  int i = blockIdx.x * 256 + threadIdx.x;    // 0 .. 2^21-1
  const float* src; u16* dst; int off;
  if (i < (1 << 20)) { src = Z; dst = Zb; off = i; }
  else {
    int j = i - (1 << 20);
    int seg = j >> 18; off = j & ((1 << 18) - 1);
    src = (seg == 0) ? Wq : (seg == 1) ? Wk : (seg == 2) ? Wv : Wo;
    dst = (seg == 0) ? Wqb : (seg == 1) ? Wkb : (seg == 2) ? Wvb : Wob;
  }
  float4 v = reinterpret_cast<const float4*>(src)[off];
  ushort4 o;
  o.x = f2bf(v.x); o.y = f2bf(v.y); o.z = f2bf(v.z); o.w = f2bf(v.w);
  reinterpret_cast<ushort4*>(dst)[off] = o;
}

// ---------------- GEMM: C = (A @ Bt^T + bias) * oscl ----------------
// TRANSV: z==2 writes output transposed per-head: Vt[(b*NH+h)*HD + d][s]
template<int F32OUT, int TRANSV>
__global__ __launch_bounds__(256, 3)
void gemm_bt(const u16* __restrict__ A,
             const u16* __restrict__ B0, const u16* __restrict__ B1, const u16* __restrict__ B2,
             const float* __restrict__ bias0, const float* __restrict__ bias1, const float* __restrict__ bias2,
             void* __restrict__ C0, void* __restrict__ C1, void* __restrict__ C2,
             float s0, float s1, float s2,
             int M, int N, int K)
{
  (void)M;
  const int z = blockIdx.z;
  const u16* Bt = (z == 0) ? B0 : ((z == 1) ? B1 : B2);
  const float* bias = (z == 0) ? bias0 : ((z == 1) ? bias1 : bias2);
  void* Cout = (z == 0) ? C0 : ((z == 1) ? C1 : C2);
  const float oscl = (z == 0) ? s0 : ((z == 1) ? s1 : s2);

  __shared__ u16 lds_a[2][128*32];
  __shared__ u16 lds_b[2][128*32];

  const int tid = threadIdx.x;
  const int w = tid >> 6, lane = tid & 63;
  const int l15 = lane & 15, lhi = lane >> 4;
  const int m0 = blockIdx.y * 128, n0 = blockIdx.x * 128;
  const int wm = w >> 1, wn = w & 1;

  f32x4 acc[4][4] = {};

  auto stage = [&](int buf, int kt) {
    const int k0 = kt * 32;
    #pragma unroll
    for (int i = 0; i < 2; ++i) {
      const int base = (w*2 + i) * 1024;
      const int pos  = base + (lane << 4);
      const int row  = pos >> 6;
      const int slot = (pos >> 4) & 3;
      const int ss   = slot ^ ((row >> 1) & 3);
      async_copy16((char*)lds_a[buf] + base,
                   (const char*)(A  + (size_t)(m0 + row) * K + k0 + ss*8));
      async_copy16((char*)lds_b[buf] + base,
                   (const char*)(Bt + (size_t)(n0 + row) * K + k0 + ss*8));
    }
  };

  auto compute = [&](int buf) {
    bf16x8 af[4], bf[4];
    #pragma unroll
    for (int mi = 0; mi < 4; ++mi) {
      const int row = wm*64 + mi*16 + l15;
      const int s   = lhi ^ ((row >> 1) & 3);
      af[mi] = *reinterpret_cast<const bf16x8*>((const char*)lds_a[buf] + row*64 + s*16);
    }
    #pragma unroll
    for (int ni = 0; ni < 4; ++ni) {
      const int row = wn*64 + ni*16 + l15;
      const int s   = lhi ^ ((row >> 1) & 3);
      bf[ni] = *reinterpret_cast<const bf16x8*>((const char*)lds_b[buf] + row*64 + s*16);
    }
    #pragma unroll
    for (int mi = 0; mi < 4; ++mi)
      #pragma unroll
      for (int ni = 0; ni < 4; ++ni)
        acc[mi][ni] = __builtin_amdgcn_mfma_f32_16x16x32_bf16(af[mi], bf[ni], acc[mi][ni], 0, 0, 0);
  };

  stage(0, 0);
  __syncthreads();
  const int nk = K >> 5;
  for (int kt = 0; kt < nk; ++kt) {
    if (kt + 1 < nk) stage((kt + 1) & 1, kt + 1);
    compute(kt & 1);
    __syncthreads();
  }

  // epilogue: C/D layout col=lane&15, row=(lane>>4)*4+reg
  #pragma unroll
  for (int mi = 0; mi < 4; ++mi) {
    const int rowb = m0 + wm*64 + mi*16 + (lhi << 2);
    #pragma unroll
    for (int ni = 0; ni < 4; ++ni) {
      const int col = n0 + wn*64 + ni*16 + l15;
      const float bb = bias[col];
      if (TRANSV && z == 2) {
        // V output transposed per head: Vt[(b*NH+h)*HD + d][s], s = rowb..rowb+3
        ushort4 o4;
        o4.x = f2bf(acc[mi][ni][0] + bb);
        o4.y = f2bf(acc[mi][ni][1] + bb);
        o4.z = f2bf(acc[mi][ni][2] + bb);
        o4.w = f2bf(acc[mi][ni][3] + bb);
        const int bb2 = rowb >> 11, s = rowb & (SEQ - 1);
        const int hh = col >> 6, dd = col & 63;
        *reinterpret_cast<ushort4*>((u16*)Cout + ((size_t)(bb2*NH + hh)*HD + dd)*SEQ + s) = o4;
      } else {
        #pragma unroll
        for (int r = 0; r < 4; ++r) {
          const float v = (acc[mi][ni][r] + bb) * oscl;
          if (F32OUT)
            reinterpret_cast<float*>(Cout)[(size_t)(rowb + r) * N + col] = v;
          else
            reinterpret_cast<u16*>(Cout)[(size_t)(rowb + r) * N + col] = f2bf(v);
        }
      }
    }
  }
}

// ---------------- fused flash attention, swapped 32x32 structure ----------------
// grid (SEQ/128, NB*NH), 256 threads = 4 waves, wave w owns q rows [bx*128+32w, +32).
// Q pre-scaled by 1/sqrt(d) in its GEMM epilogue.
// S^T = mfma(A=K, B=Q): lane holds q = lane&31 fixed, 32 key-scores in regs.
// O^T = mfma(A=V^T, B=P^T). V^T comes pre-transposed from the V-GEMM (Vt global,
// d-major), staged to LDS [d][slot] with slot-XOR swizzle: LDS slot s_l of row d
// holds global key-slot s_l ^ (d&7) (pre-swizzled global source, linear LDS dest;
// read applies the same XOR -> conflict-reduced ds_read_b128).
__global__ __launch_bounds__(256, 2)
void attn32(const u16* __restrict__ Qb, const u16* __restrict__ Kb,
            const u16* __restrict__ Vt, u16* __restrict__ Ob)
{
  __shared__ u16 vt[2][64*64];   // [d 0..63][8 slots of 8 keys], double-buffered

  const int tid = threadIdx.x;
  const int w = tid >> 6, lane = tid & 63;
  const int l31 = lane & 31, hi = lane >> 5;
  const int bh = blockIdx.y, b = bh >> 4, h = bh & 15;
  const int qrow = blockIdx.x * 128 + w * 32 + l31;

  // Q frags (B-operand: n=q=l31, k = kc*16 + hi*8 + j), hoisted
  bf16x8 qf[4];
  {
    const u16* qp = Qb + (size_t)(b*SEQ + qrow) * D_MODEL + h*HD + hi*8;
    #pragma unroll
    for (int kc = 0; kc < 4; ++kc)
      qf[kc] = *reinterpret_cast<const bf16x8*>(qp + kc*16);
  }

  const u16* Vtg = Vt + (size_t)bh * HD * SEQ;   // this (b,h)'s [64][2048] slab

  float mrun = -1e30f, lrun = 0.f;
  f32x16 o0 = {}, o1 = {};

  auto stageV = [&](int buf, int kv0) {
    #pragma unroll
    for (int i = 0; i < 2; ++i) {
      const int c = i*256 + tid;        // chunk 0..511
      const int d = c >> 3;             // 0..63
      const int sl = c & 7;             // LDS slot within row d
      const int sg = sl ^ (d & 7);      // inverse-swizzled global key-slot
      async_copy16((char*)vt[buf] + (size_t)(i*256 + w*64)*16,
                   (const char*)(Vtg + (size_t)d*SEQ + kv0 + sg*8));
    }
  };

  stageV(0, 0);
  __syncthreads();
  int buf = 0;

  for (int kv0 = 0; kv0 < SEQ; kv0 += 64) {
    if (kv0 + 64 < SEQ) stageV(buf ^ 1, kv0 + 64);   // prefetch (drained by end barrier)

    // ---- S^T = K · Q^T : s0 = keys [kv0,kv0+32), s1 = [kv0+32,kv0+64)
    f32x16 s0 = {}, s1 = {};
    {
      const u16* kp = Kb + (size_t)(b*SEQ + kv0 + l31) * D_MODEL + h*HD + hi*8;
      #pragma unroll
      for (int kc = 0; kc < 4; ++kc) {
        bf16x8 ka = *reinterpret_cast<const bf16x8*>(kp + kc*16);
        s0 = __builtin_amdgcn_mfma_f32_32x32x16_bf16(ka, qf[kc], s0, 0, 0, 0);
      }
      const u16* kp1 = kp + (size_t)32 * D_MODEL;
      #pragma unroll
      for (int kc = 0; kc < 4; ++kc) {
        bf16x8 ka = *reinterpret_cast<const bf16x8*>(kp1 + kc*16);
        s1 = __builtin_amdgcn_mfma_f32_32x32x16_bf16(ka, qf[kc], s1, 0, 0, 0);
      }
    }

    // ---- online softmax (lane owns one q; partner lane^32 has other 32 keys)
    float tmax = s0[0];
    #pragma unroll
    for (int r = 1; r < 16; ++r) tmax = fmaxf(tmax, s0[r]);
    #pragma unroll
    for (int r = 0; r < 16; ++r) tmax = fmaxf(tmax, s1[r]);
    tmax = fmaxf(tmax, __shfl_xor(tmax, 32));
    const float mnew = fmaxf(mrun, tmax);
    float rs = 0.f;
    #pragma unroll
    for (int r = 0; r < 16; ++r) { s0[r] = __expf(s0[r] - mnew); rs += s0[r]; }
    #pragma unroll
    for (int r = 0; r < 16; ++r) { s1[r] = __expf(s1[r] - mnew); rs += s1[r]; }
    rs += __shfl_xor(rs, 32);
    const float a = __expf(mrun - mnew);   // 0 on first tile
    lrun = lrun * a + rs;
    mrun = mnew;
    #pragma unroll
    for (int r = 0; r < 16; ++r) { o0[r] *= a; o1[r] *= a; }

    // ---- pack P: pwA[kb][a4*2+z] = keys kb*32 + 8*a4 + 4*hi + {2z, 2z+1}
    //      (C/D row formula: key(r) = (r&3) + 8*(r>>2) + 4*hi)
    unsigned pwA[2][8];
    #pragma unroll
    for (int a4 = 0; a4 < 4; ++a4)
      #pragma unroll
      for (int zz = 0; zz < 2; ++zz) {
        pwA[0][a4*2+zz] = (unsigned)f2bf(s0[4*a4+2*zz]) | ((unsigned)f2bf(s0[4*a4+2*zz+1]) << 16);
        pwA[1][a4*2+zz] = (unsigned)f2bf(s1[4*a4+2*zz]) | ((unsigned)f2bf(s1[4*a4+2*zz+1]) << 16);
      }

    // ---- O^T += V^T · P^T over 4 key-steps of 16
    const char* vb = (const char*)vt[buf];
    #pragma unroll
    for (int ks = 0; ks < 4; ++ks) {
      const int kb = ks >> 1, sm = ks & 1;
      // B-frag (P^T): lane needs keys ks*16 + hi*8 + {0..7}
      unsigned keep0 = hi ? pwA[kb][(2*sm+1)*2+0] : pwA[kb][(2*sm)*2+0];
      unsigned keep1 = hi ? pwA[kb][(2*sm+1)*2+1] : pwA[kb][(2*sm)*2+1];
      unsigned send0 = hi ? pwA[kb][(2*sm)*2+0]   : pwA[kb][(2*sm+1)*2+0];
      unsigned send1 = hi ? pwA[kb][(2*sm)*2+1]   : pwA[kb][(2*sm+1)*2+1];
      unsigned recv0 = (unsigned)__shfl_xor((int)send0, 32);
      unsigned recv1 = (unsigned)__shfl_xor((int)send1, 32);
      union { bf16x8 f; unsigned u[4]; } pf;
      pf.u[0] = hi ? recv0 : keep0;
      pf.u[1] = hi ? recv1 : keep1;
      pf.u[2] = hi ? keep0 : recv0;
      pf.u[3] = hi ? keep1 : recv1;

      // A-frags (V^T): one b128 each, logical slot ks*2+hi, XOR-unswizzled
      const int slg = ks*2 + hi;
      const int sw  = slg ^ (l31 & 7);         // (l31&7) == ((l31+32)&7)
      bf16x8 va0 = *reinterpret_cast<const bf16x8*>(vb + (size_t)(l31*8 + sw)*16);
      bf16x8 va1 = *reinterpret_cast<const bf16x8*>(vb + (size_t)((l31+32)*8 + sw)*16);

      o0 = __builtin_amdgcn_mfma_f32_32x32x16_bf16(va0, pf.f, o0, 0, 0, 0);
      o1 = __builtin_amdgcn_mfma_f32_32x32x16_bf16(va1, pf.f, o1, 0, 0, 0);
    }

    __syncthreads();   // drains prefetch (vmcnt 0) + protects vt[buf] reuse
    buf ^= 1;
  }

  // ---- epilogue: O^T[d][q] -> Ob[b, q, h*64 + d], d = 8*a4 + 4*hi + j (+32 for o1)
  const float inv = 1.0f / lrun;
  u16* op = Ob + (size_t)(b*SEQ + qrow) * D_MODEL + h*HD;
  #pragma unroll
  for (int a4 = 0; a4 < 4; ++a4) {
    ushort4 v0, v1;
    v0.x = f2bf(o0[4*a4+0]*inv); v0.y = f2bf(o0[4*a4+1]*inv);
    v0.z = f2bf(o0[4*a4+2]*inv); v0.w = f2bf(o0[4*a4+3]*inv);
    v1.x = f2bf(o1[4*a4+0]*inv); v1.y = f2bf(o1[4*a4+1]*inv);
    v1.z = f2bf(o1[4*a4+2]*inv); v1.w = f2bf(o1[4*a4+3]*inv);
    *reinterpret_cast<ushort4*>(op + 8*a4 + 4*hi)      = v0;
    *reinterpret_cast<ushort4*>(op + 32 + 8*a4 + 4*hi) = v1;
  }
}

// ---------------- launcher ----------------
extern "C" void kernel_launch(void* const* d_in, const int* in_sizes, int n_in,
                              void* d_out, int out_size, void* d_ws, size_t ws_size,
                              hipStream_t stream)
{
  (void)in_sizes; (void)n_in; (void)out_size;
  const float* Z  = (const float*)d_in[0];
  const float* Wq = (const float*)d_in[1];
  const float* bq = (const float*)d_in[2];
  const float* Wk = (const float*)d_in[3];
  const float* bk = (const float*)d_in[4];
  const float* Wv = (const float*)d_in[5];
  const float* bv = (const float*)d_in[6];
  const float* Wo = (const float*)d_in[7];
  const float* bo = (const float*)d_in[8];
  float* out = (float*)d_out;

  const size_t needed = (size_t)(M_TOT*D_MODEL)*2*5 + (size_t)(D_MODEL*D_MODEL)*2*4;
  if (ws_size < needed) return;

  u16* Zb  = (u16*)d_ws;
  u16* Wqb = Zb  + (size_t)M_TOT*D_MODEL;
  u16* Wkb = Wqb + (size_t)D_MODEL*D_MODEL;
  u16* Wvb = Wkb + (size_t)D_MODEL*D_MODEL;
  u16* Wob = Wvb + (size_t)D_MODEL*D_MODEL;
  u16* Qb  = Wob + (size_t)D_MODEL*D_MODEL;
  u16* Kb  = Qb  + (size_t)M_TOT*D_MODEL;
  u16* Vt  = Kb  + (size_t)M_TOT*D_MODEL;   // [b*NH+h][HD][SEQ]
  u16* Ab  = Vt  + (size_t)M_TOT*D_MODEL;

  cvt_all<<<dim3(8192), 256, 0, stream>>>(Z, Wq, Wk, Wv, Wo, Zb, Wqb, Wkb, Wvb, Wob);

  // QKV projections (Q epilogue pre-scaled by 1/sqrt(d); V written transposed per head)
  dim3 gproj(D_MODEL/128, M_TOT/128, 3);
  gemm_bt<0,1><<<gproj, 256, 0, stream>>>(Zb, Wqb, Wkb, Wvb, bq, bk, bv,
                                          (void*)Qb, (void*)Kb, (void*)Vt,
                                          ATT_SCALE, 1.0f, 1.0f,
                                          M_TOT, D_MODEL, D_MODEL);

  dim3 gattn(SEQ/128, NB*NH);
  attn32<<<gattn, 256, 0, stream>>>(Qb, Kb, Vt, Ab);

  dim3 gout(D_MODEL/128, M_TOT/128, 1);
  gemm_bt<1,0><<<gout, 256, 0, stream>>>(Ab, Wob, Wob, Wob, bo, bo, bo,
                                         (void*)out, (void*)out, (void*)out,
                                         1.0f, 1.0f, 1.0f,
                                         M_TOT, D_MODEL, D_MODEL);
}

// Round 5
// 238.966 us; speedup vs baseline: 1.3365x; 1.0067x over previous
//
#include <hip/hip_runtime.h>
#include <hip/hip_bf16.h>
#include <stdint.h>

typedef unsigned short u16;
typedef __bf16 bf16x8 __attribute__((ext_vector_type(8)));
typedef float f32x4 __attribute__((ext_vector_type(4)));
typedef float f32x16 __attribute__((ext_vector_type(16)));

#define D_MODEL 1024
#define SEQ     2048
#define NB      2
#define NH      16
#define HD      64
#define M_TOT   (NB*SEQ)        // 4096
// attention scale folded with log2(e): scores come out in log2 domain
#define QSCALE  (0.125f * 1.44269504088896f)
#define DEFER_THR 8.0f          // log2-domain defer-max threshold (P <= 2^8)

__device__ __forceinline__ u16 f2bf(float f) {
  union { __bf16 b; u16 u; } cv; cv.b = (__bf16)f; return cv.u;
}
__device__ __forceinline__ float exp2_fast(float x) {
  return __builtin_amdgcn_exp2f(x);
}

// async global->LDS, 16B per lane. lds_dst must be wave-uniform (HW adds lane*16).
__device__ __forceinline__ void async_copy16(void* lds_dst, const void* gsrc) {
  __builtin_amdgcn_global_load_lds(
      (const __attribute__((address_space(1))) unsigned int*)gsrc,
      (__attribute__((address_space(3))) unsigned int*)lds_dst, 16, 0, 0);
}

// ---------------- fused f32 -> bf16 convert for Z + 4 weights ----------------
__global__ void cvt_all(const float* __restrict__ Z,  const float* __restrict__ Wq,
                        const float* __restrict__ Wk, const float* __restrict__ Wv,
                        const float* __restrict__ Wo,
                        u16* __restrict__ Zb,  u16* __restrict__ Wqb,
                        u16* __restrict__ Wkb, u16* __restrict__ Wvb,
                        u16* __restrict__ Wob)
{
  int i = blockIdx.x * 256 + threadIdx.x;    // 0 .. 2^21-1
  const float* src; u16* dst; int off;
  if (i < (1 << 20)) { src = Z; dst = Zb; off = i; }
  else {
    int j = i - (1 << 20);
    int seg = j >> 18; off = j & ((1 << 18) - 1);
    src = (seg == 0) ? Wq : (seg == 1) ? Wk : (seg == 2) ? Wv : Wo;
    dst = (seg == 0) ? Wqb : (seg == 1) ? Wkb : (seg == 2) ? Wvb : Wob;
  }
  float4 v = reinterpret_cast<const float4*>(src)[off];
  ushort4 o;
  o.x = f2bf(v.x); o.y = f2bf(v.y); o.z = f2bf(v.z); o.w = f2bf(v.w);
  reinterpret_cast<ushort4*>(dst)[off] = o;
}

// ---------------- GEMM: C = (A @ Bt^T + bias) * oscl ----------------
// TRANSV && z==2: computes C^T via swapped-operand MFMA and writes
// Vt[(b*NH+h)*HD + d][s] with 16-lane-contiguous stores.
template<int F32OUT, int TRANSV>
__global__ __launch_bounds__(256, 3)
void gemm_bt(const u16* __restrict__ A,
             const u16* __restrict__ B0, const u16* __restrict__ B1, const u16* __restrict__ B2,
             const float* __restrict__ bias0, const float* __restrict__ bias1, const float* __restrict__ bias2,
             void* __restrict__ C0, void* __restrict__ C1, void* __restrict__ C2,
             float s0, float s1, float s2,
             int M, int N, int K)
{
  (void)M;
  const int z = blockIdx.z;
  const u16* Bt = (z == 0) ? B0 : ((z == 1) ? B1 : B2);
  const float* bias = (z == 0) ? bias0 : ((z == 1) ? bias1 : bias2);
  void* Cout = (z == 0) ? C0 : ((z == 1) ? C1 : C2);
  const float oscl = (z == 0) ? s0 : ((z == 1) ? s1 : s2);
  const bool vswap = TRANSV && (z == 2);

  __shared__ u16 lds_a[2][128*32];
  __shared__ u16 lds_b[2][128*32];

  const int tid = threadIdx.x;
  const int w = tid >> 6, lane = tid & 63;
  const int l15 = lane & 15, lhi = lane >> 4;
  const int m0 = blockIdx.y * 128, n0 = blockIdx.x * 128;
  const int wm = w >> 1, wn = w & 1;

  f32x4 acc[4][4] = {};

  auto stage = [&](int buf, int kt) {
    const int k0 = kt * 32;
    #pragma unroll
    for (int i = 0; i < 2; ++i) {
      const int base = (w*2 + i) * 1024;
      const int pos  = base + (lane << 4);
      const int row  = pos >> 6;
      const int slot = (pos >> 4) & 3;
      const int ss   = slot ^ ((row >> 1) & 3);
      async_copy16((char*)lds_a[buf] + base,
                   (const char*)(A  + (size_t)(m0 + row) * K + k0 + ss*8));
      async_copy16((char*)lds_b[buf] + base,
                   (const char*)(Bt + (size_t)(n0 + row) * K + k0 + ss*8));
    }
  };

  auto compute = [&](int buf) {
    bf16x8 af[4], bf[4];
    #pragma unroll
    for (int mi = 0; mi < 4; ++mi) {
      const int row = wm*64 + mi*16 + l15;
      const int s   = lhi ^ ((row >> 1) & 3);
      af[mi] = *reinterpret_cast<const bf16x8*>((const char*)lds_a[buf] + row*64 + s*16);
    }
    #pragma unroll
    for (int ni = 0; ni < 4; ++ni) {
      const int row = wn*64 + ni*16 + l15;
      const int s   = lhi ^ ((row >> 1) & 3);
      bf[ni] = *reinterpret_cast<const bf16x8*>((const char*)lds_b[buf] + row*64 + s*16);
    }
    if (vswap) {
      #pragma unroll
      for (int mi = 0; mi < 4; ++mi)
        #pragma unroll
        for (int ni = 0; ni < 4; ++ni)
          acc[mi][ni] = __builtin_amdgcn_mfma_f32_16x16x32_bf16(bf[ni], af[mi], acc[mi][ni], 0, 0, 0);
    } else {
      #pragma unroll
      for (int mi = 0; mi < 4; ++mi)
        #pragma unroll
        for (int ni = 0; ni < 4; ++ni)
          acc[mi][ni] = __builtin_amdgcn_mfma_f32_16x16x32_bf16(af[mi], bf[ni], acc[mi][ni], 0, 0, 0);
    }
  };

  stage(0, 0);
  __syncthreads();
  const int nk = K >> 5;
  for (int kt = 0; kt < nk; ++kt) {
    if (kt + 1 < nk) stage((kt + 1) & 1, kt + 1);
    compute(kt & 1);
    __syncthreads();
  }

  if (vswap) {
    // acc[mi][ni] = C^T frag: d = n0+wn*64+ni*16+lhi*4+r, s = m0+wm*64+mi*16+l15
    #pragma unroll
    for (int mi = 0; mi < 4; ++mi) {
      const int sglob = m0 + wm*64 + mi*16 + l15;
      const int b2 = sglob >> 11, s = sglob & (SEQ - 1);
      #pragma unroll
      for (int ni = 0; ni < 4; ++ni) {
        #pragma unroll
        for (int r = 0; r < 4; ++r) {
          const int dglob = n0 + wn*64 + ni*16 + (lhi << 2) + r;
          const int hh = dglob >> 6, dd = dglob & 63;
          const float v = acc[mi][ni][r] + bias[dglob];
          reinterpret_cast<u16*>(Cout)[((size_t)(b2*NH + hh)*HD + dd)*SEQ + s] = f2bf(v);
        }
      }
    }
  } else {
    // C/D layout col=lane&15, row=(lane>>4)*4+reg
    #pragma unroll
    for (int mi = 0; mi < 4; ++mi) {
      const int rowb = m0 + wm*64 + mi*16 + (lhi << 2);
      #pragma unroll
      for (int ni = 0; ni < 4; ++ni) {
        const int col = n0 + wn*64 + ni*16 + l15;
        const float bb = bias[col];
        #pragma unroll
        for (int r = 0; r < 4; ++r) {
          const float v = (acc[mi][ni][r] + bb) * oscl;
          if (F32OUT)
            reinterpret_cast<float*>(Cout)[(size_t)(rowb + r) * N + col] = v;
          else
            reinterpret_cast<u16*>(Cout)[(size_t)(rowb + r) * N + col] = f2bf(v);
        }
      }
    }
  }
}

// ---------------- fused flash attention, swapped 32x32 structure ----------------
// grid (SEQ/128, NB*NH), 256 threads = 4 waves, wave w owns q rows [bx*128+32w, +32).
// Q pre-scaled by log2(e)/sqrt(d): scores in log2 domain, exp2 softmax.
// K and V^T both staged in LDS (double-buffered, global_load_lds, XOR slot swizzle:
// LDS slot sl of row rr holds global slot sl ^ (rr&7); read applies same XOR).
__global__ __launch_bounds__(256, 2)
void attn32(const u16* __restrict__ Qb, const u16* __restrict__ Kb,
            const u16* __restrict__ Vt, u16* __restrict__ Ob)
{
  __shared__ u16 vt[2][64*64];   // [d][8 slots of 8 keys]
  __shared__ u16 kt[2][64*64];   // [key][8 slots of 8 d]

  const int tid = threadIdx.x;
  const int w = tid >> 6, lane = tid & 63;
  const int l31 = lane & 31, hi = lane >> 5;
  const int bh = blockIdx.y, b = bh >> 4, h = bh & 15;
  const int qrow = blockIdx.x * 128 + w * 32 + l31;

  // Q frags (B-operand: n=q=l31, k = kc*16 + hi*8 + j), hoisted
  bf16x8 qf[4];
  {
    const u16* qp = Qb + (size_t)(b*SEQ + qrow) * D_MODEL + h*HD + hi*8;
    #pragma unroll
    for (int kc = 0; kc < 4; ++kc)
      qf[kc] = *reinterpret_cast<const bf16x8*>(qp + kc*16);
  }

  const u16* Vtg = Vt + (size_t)bh * HD * SEQ;            // [64 d][2048 s]
  const u16* Kg  = Kb + (size_t)(b*SEQ) * D_MODEL + h*HD; // rows [s][64 d]

  float mrun = -1e30f, lrun = 0.f;
  f32x16 o0 = {}, o1 = {};

  auto stageKV = [&](int buf, int kv0) {
    #pragma unroll
    for (int i = 0; i < 2; ++i) {
      const int c = i*256 + tid;        // chunk 0..511
      const int d = c >> 3;
      const int sl = c & 7;
      const int sg = sl ^ (d & 7);
      async_copy16((char*)vt[buf] + (size_t)(i*256 + w*64)*16,
                   (const char*)(Vtg + (size_t)d*SEQ + kv0 + sg*8));
    }
    #pragma unroll
    for (int i = 0; i < 2; ++i) {
      const int c = i*256 + tid;
      const int key = c >> 3;
      const int sl = c & 7;
      const int sg = sl ^ (key & 7);
      async_copy16((char*)kt[buf] + (size_t)(i*256 + w*64)*16,
                   (const char*)(Kg + (size_t)(kv0 + key)*D_MODEL + sg*8));
    }
  };

  stageKV(0, 0);
  __syncthreads();
  int buf = 0;

  for (int kv0 = 0; kv0 < SEQ; kv0 += 64) {
    if (kv0 + 64 < SEQ) stageKV(buf ^ 1, kv0 + 64);   // prefetch (drains at end barrier)

    // ---- S^T = K · Q^T from LDS: s0 = keys [kv0,kv0+32), s1 = [+32,+64)
    f32x16 s0 = {}, s1 = {};
    {
      const char* kbp = (const char*)kt[buf];
      #pragma unroll
      for (int kc = 0; kc < 4; ++kc) {
        const int sw = (kc*2 + hi) ^ (l31 & 7);   // same for row l31 and l31+32
        bf16x8 ka0 = *reinterpret_cast<const bf16x8*>(kbp + (size_t)(l31*8 + sw)*16);
        s0 = __builtin_amdgcn_mfma_f32_32x32x16_bf16(ka0, qf[kc], s0, 0, 0, 0);
        bf16x8 ka1 = *reinterpret_cast<const bf16x8*>(kbp + (size_t)((l31+32)*8 + sw)*16);
        s1 = __builtin_amdgcn_mfma_f32_32x32x16_bf16(ka1, qf[kc], s1, 0, 0, 0);
      }
    }

    // ---- online softmax, log2 domain, defer-max
    float tmax = s0[0];
    #pragma unroll
    for (int r = 1; r < 16; ++r) tmax = fmaxf(tmax, s0[r]);
    #pragma unroll
    for (int r = 0; r < 16; ++r) tmax = fmaxf(tmax, s1[r]);
    tmax = fmaxf(tmax, __shfl_xor(tmax, 32));
    if (!__all(tmax - mrun <= DEFER_THR)) {
      const float mnew = fmaxf(mrun, tmax);
      const float a = exp2_fast(mrun - mnew);    // 0 on first tile
      lrun *= a;
      #pragma unroll
      for (int r = 0; r < 16; ++r) { o0[r] *= a; o1[r] *= a; }
      mrun = mnew;
    }
    float rs = 0.f;
    #pragma unroll
    for (int r = 0; r < 16; ++r) { s0[r] = exp2_fast(s0[r] - mrun); rs += s0[r]; }
    #pragma unroll
    for (int r = 0; r < 16; ++r) { s1[r] = exp2_fast(s1[r] - mrun); rs += s1[r]; }
    rs += __shfl_xor(rs, 32);
    lrun += rs;

    // ---- pack P: pwA[kb][a4*2+z] = keys kb*32 + 8*a4 + 4*hi + {2z, 2z+1}
    unsigned pwA[2][8];
    #pragma unroll
    for (int a4 = 0; a4 < 4; ++a4)
      #pragma unroll
      for (int zz = 0; zz < 2; ++zz) {
        pwA[0][a4*2+zz] = (unsigned)f2bf(s0[4*a4+2*zz]) | ((unsigned)f2bf(s0[4*a4+2*zz+1]) << 16);
        pwA[1][a4*2+zz] = (unsigned)f2bf(s1[4*a4+2*zz]) | ((unsigned)f2bf(s1[4*a4+2*zz+1]) << 16);
      }

    // ---- O^T += V^T · P^T over 4 key-steps of 16
    const char* vb = (const char*)vt[buf];
    #pragma unroll
    for (int ks = 0; ks < 4; ++ks) {
      const int kb = ks >> 1, sm = ks & 1;
      unsigned keep0 = hi ? pwA[kb][(2*sm+1)*2+0] : pwA[kb][(2*sm)*2+0];
      unsigned keep1 = hi ? pwA[kb][(2*sm+1)*2+1] : pwA[kb][(2*sm)*2+1];
      unsigned send0 = hi ? pwA[kb][(2*sm)*2+0]   : pwA[kb][(2*sm+1)*2+0];
      unsigned send1 = hi ? pwA[kb][(2*sm)*2+1]   : pwA[kb][(2*sm+1)*2+1];
      unsigned recv0 = (unsigned)__shfl_xor((int)send0, 32);
      unsigned recv1 = (unsigned)__shfl_xor((int)send1, 32);
      union { bf16x8 f; unsigned u[4]; } pf;
      pf.u[0] = hi ? recv0 : keep0;
      pf.u[1] = hi ? recv1 : keep1;
      pf.u[2] = hi ? keep0 : recv0;
      pf.u[3] = hi ? keep1 : recv1;

      const int slg = ks*2 + hi;
      const int sw  = slg ^ (l31 & 7);
      bf16x8 va0 = *reinterpret_cast<const bf16x8*>(vb + (size_t)(l31*8 + sw)*16);
      bf16x8 va1 = *reinterpret_cast<const bf16x8*>(vb + (size_t)((l31+32)*8 + sw)*16);

      o0 = __builtin_amdgcn_mfma_f32_32x32x16_bf16(va0, pf.f, o0, 0, 0, 0);
      o1 = __builtin_amdgcn_mfma_f32_32x32x16_bf16(va1, pf.f, o1, 0, 0, 0);
    }

    __syncthreads();   // drains prefetch (vmcnt 0) + protects kt/vt[buf] reuse
    buf ^= 1;
  }

  // ---- epilogue: O^T[d][q] -> Ob[b, q, h*64 + d], d = 8*a4 + 4*hi + j (+32 for o1)
  const float inv = 1.0f / lrun;
  u16* op = Ob + (size_t)(b*SEQ + qrow) * D_MODEL + h*HD;
  #pragma unroll
  for (int a4 = 0; a4 < 4; ++a4) {
    ushort4 v0, v1;
    v0.x = f2bf(o0[4*a4+0]*inv); v0.y = f2bf(o0[4*a4+1]*inv);
    v0.z = f2bf(o0[4*a4+2]*inv); v0.w = f2bf(o0[4*a4+3]*inv);
    v1.x = f2bf(o1[4*a4+0]*inv); v1.y = f2bf(o1[4*a4+1]*inv);
    v1.z = f2bf(o1[4*a4+2]*inv); v1.w = f2bf(o1[4*a4+3]*inv);
    *reinterpret_cast<ushort4*>(op + 8*a4 + 4*hi)      = v0;
    *reinterpret_cast<ushort4*>(op + 32 + 8*a4 + 4*hi) = v1;
  }
}

// ---------------- launcher ----------------
extern "C" void kernel_launch(void* const* d_in, const int* in_sizes, int n_in,
                              void* d_out, int out_size, void* d_ws, size_t ws_size,
                              hipStream_t stream)
{
  (void)in_sizes; (void)n_in; (void)out_size;
  const float* Z  = (const float*)d_in[0];
  const float* Wq = (const float*)d_in[1];
  const float* bq = (const float*)d_in[2];
  const float* Wk = (const float*)d_in[3];
  const float* bk = (const float*)d_in[4];
  const float* Wv = (const float*)d_in[5];
  const float* bv = (const float*)d_in[6];
  const float* Wo = (const float*)d_in[7];
  const float* bo = (const float*)d_in[8];
  float* out = (float*)d_out;

  const size_t needed = (size_t)(M_TOT*D_MODEL)*2*5 + (size_t)(D_MODEL*D_MODEL)*2*4;
  if (ws_size < needed) return;

  u16* Zb  = (u16*)d_ws;
  u16* Wqb = Zb  + (size_t)M_TOT*D_MODEL;
  u16* Wkb = Wqb + (size_t)D_MODEL*D_MODEL;
  u16* Wvb = Wkb + (size_t)D_MODEL*D_MODEL;
  u16* Wob = Wvb + (size_t)D_MODEL*D_MODEL;
  u16* Qb  = Wob + (size_t)D_MODEL*D_MODEL;
  u16* Kb  = Qb  + (size_t)M_TOT*D_MODEL;
  u16* Vt  = Kb  + (size_t)M_TOT*D_MODEL;   // [b*NH+h][HD][SEQ]
  u16* Ab  = Vt  + (size_t)M_TOT*D_MODEL;

  cvt_all<<<dim3(8192), 256, 0, stream>>>(Z, Wq, Wk, Wv, Wo, Zb, Wqb, Wkb, Wvb, Wob);

  // QKV projections (Q epilogue pre-scaled by log2e/sqrt(d); V written transposed)
  dim3 gproj(D_MODEL/128, M_TOT/128, 3);
  gemm_bt<0,1><<<gproj, 256, 0, stream>>>(Zb, Wqb, Wkb, Wvb, bq, bk, bv,
                                          (void*)Qb, (void*)Kb, (void*)Vt,
                                          QSCALE, 1.0f, 1.0f,
                                          M_TOT, D_MODEL, D_MODEL);

  dim3 gattn(SEQ/128, NB*NH);
  attn32<<<gattn, 256, 0, stream>>>(Qb, Kb, Vt, Ab);

  dim3 gout(D_MODEL/128, M_TOT/128, 1);
  gemm_bt<1,0><<<gout, 256, 0, stream>>>(Ab, Wob, Wob, Wob, bo, bo, bo,
                                         (void*)out, (void*)out, (void*)out,
                                         1.0f, 1.0f, 1.0f,
                                         M_TOT, D_MODEL, D_MODEL);
}

// Round 6
// 237.234 us; speedup vs baseline: 1.3462x; 1.0073x over previous
//
#include <hip/hip_runtime.h>
#include <hip/hip_bf16.h>
#include <stdint.h>

typedef unsigned short u16;
typedef __bf16 bf16x8 __attribute__((ext_vector_type(8)));
typedef float f32x4 __attribute__((ext_vector_type(4)));
typedef float f32x16 __attribute__((ext_vector_type(16)));

#define D_MODEL 1024
#define SEQ     2048
#define NB      2
#define NH      16
#define HD      64
#define M_TOT   (NB*SEQ)        // 4096
// attention scale folded with log2(e): scores come out in log2 domain
#define QSCALE  (0.125f * 1.44269504088896f)
#define DEFER_THR 8.0f          // log2-domain defer-max threshold (P <= 2^8)

__device__ __forceinline__ u16 f2bf(float f) {
  union { __bf16 b; u16 u; } cv; cv.b = (__bf16)f; return cv.u;
}
__device__ __forceinline__ float exp2_fast(float x) {
  return __builtin_amdgcn_exp2f(x);
}

// async global->LDS, 16B per lane. lds_dst must be wave-uniform (HW adds lane*16).
__device__ __forceinline__ void async_copy16(void* lds_dst, const void* gsrc) {
  __builtin_amdgcn_global_load_lds(
      (const __attribute__((address_space(1))) unsigned int*)gsrc,
      (__attribute__((address_space(3))) unsigned int*)lds_dst, 16, 0, 0);
}

// counted waits: tile-k loads are the oldest 4 per thread; allow 2 tiles in flight
__device__ __forceinline__ void wait_tile(int kt, int nk) {
  if (kt + 2 < nk)      { asm volatile("s_waitcnt vmcnt(8)" ::: "memory"); }
  else if (kt + 1 < nk) { asm volatile("s_waitcnt vmcnt(4)" ::: "memory"); }
  else                  { asm volatile("s_waitcnt vmcnt(0)" ::: "memory"); }
  __builtin_amdgcn_sched_barrier(0);
  __builtin_amdgcn_s_barrier();
  __builtin_amdgcn_sched_barrier(0);
}

// ---------------- fused f32 -> bf16 convert for Z + 4 weights ----------------
__global__ void cvt_all(const float* __restrict__ Z,  const float* __restrict__ Wq,
                        const float* __restrict__ Wk, const float* __restrict__ Wv,
                        const float* __restrict__ Wo,
                        u16* __restrict__ Zb,  u16* __restrict__ Wqb,
                        u16* __restrict__ Wkb, u16* __restrict__ Wvb,
                        u16* __restrict__ Wob)
{
  int i = blockIdx.x * 256 + threadIdx.x;    // 0 .. 2^21-1
  const float* src; u16* dst; int off;
  if (i < (1 << 20)) { src = Z; dst = Zb; off = i; }
  else {
    int j = i - (1 << 20);
    int seg = j >> 18; off = j & ((1 << 18) - 1);
    src = (seg == 0) ? Wq : (seg == 1) ? Wk : (seg == 2) ? Wv : Wo;
    dst = (seg == 0) ? Wqb : (seg == 1) ? Wkb : (seg == 2) ? Wvb : Wob;
  }
  float4 v = reinterpret_cast<const float4*>(src)[off];
  ushort4 o;
  o.x = f2bf(v.x); o.y = f2bf(v.y); o.z = f2bf(v.z); o.w = f2bf(v.w);
  reinterpret_cast<ushort4*>(dst)[off] = o;
}

// ---------------- GEMM: C = (A @ Bt^T + bias) * oscl ----------------
// 3-stage LDS pipeline, counted vmcnt (never drains prefetch in steady state).
// TRANSV && z==2: computes C^T via swapped-operand MFMA and writes
// Vt[(b*NH+h)*HD + d][s] with 16-lane-contiguous stores.
template<int F32OUT, int TRANSV>
__global__ __launch_bounds__(256, 3)
void gemm_bt(const u16* __restrict__ A,
             const u16* __restrict__ B0, const u16* __restrict__ B1, const u16* __restrict__ B2,
             const float* __restrict__ bias0, const float* __restrict__ bias1, const float* __restrict__ bias2,
             void* __restrict__ C0, void* __restrict__ C1, void* __restrict__ C2,
             float s0, float s1, float s2,
             int M, int N, int K)
{
  (void)M;
  const int z = blockIdx.z;
  const u16* Bt = (z == 0) ? B0 : ((z == 1) ? B1 : B2);
  const float* bias = (z == 0) ? bias0 : ((z == 1) ? bias1 : bias2);
  void* Cout = (z == 0) ? C0 : ((z == 1) ? C1 : C2);
  const float oscl = (z == 0) ? s0 : ((z == 1) ? s1 : s2);
  const bool vswap = TRANSV && (z == 2);

  __shared__ u16 lds_a[3][128*32];   // 3-deep pipeline: 48KB total
  __shared__ u16 lds_b[3][128*32];

  const int tid = threadIdx.x;
  const int w = tid >> 6, lane = tid & 63;
  const int l15 = lane & 15, lhi = lane >> 4;
  const int m0 = blockIdx.y * 128, n0 = blockIdx.x * 128;
  const int wm = w >> 1, wn = w & 1;

  f32x4 acc[4][4] = {};

  auto stage = [&](int buf, int kt) {
    const int k0 = kt * 32;
    #pragma unroll
    for (int i = 0; i < 2; ++i) {
      const int base = (w*2 + i) * 1024;
      const int pos  = base + (lane << 4);
      const int row  = pos >> 6;
      const int slot = (pos >> 4) & 3;
      const int ss   = slot ^ ((row >> 1) & 3);
      async_copy16((char*)lds_a[buf] + base,
                   (const char*)(A  + (size_t)(m0 + row) * K + k0 + ss*8));
      async_copy16((char*)lds_b[buf] + base,
                   (const char*)(Bt + (size_t)(n0 + row) * K + k0 + ss*8));
    }
  };

  auto compute = [&](int buf) {
    bf16x8 af[4], bf[4];
    #pragma unroll
    for (int mi = 0; mi < 4; ++mi) {
      const int row = wm*64 + mi*16 + l15;
      const int s   = lhi ^ ((row >> 1) & 3);
      af[mi] = *reinterpret_cast<const bf16x8*>((const char*)lds_a[buf] + row*64 + s*16);
    }
    #pragma unroll
    for (int ni = 0; ni < 4; ++ni) {
      const int row = wn*64 + ni*16 + l15;
      const int s   = lhi ^ ((row >> 1) & 3);
      bf[ni] = *reinterpret_cast<const bf16x8*>((const char*)lds_b[buf] + row*64 + s*16);
    }
    if (vswap) {
      #pragma unroll
      for (int mi = 0; mi < 4; ++mi)
        #pragma unroll
        for (int ni = 0; ni < 4; ++ni)
          acc[mi][ni] = __builtin_amdgcn_mfma_f32_16x16x32_bf16(bf[ni], af[mi], acc[mi][ni], 0, 0, 0);
    } else {
      #pragma unroll
      for (int mi = 0; mi < 4; ++mi)
        #pragma unroll
        for (int ni = 0; ni < 4; ++ni)
          acc[mi][ni] = __builtin_amdgcn_mfma_f32_16x16x32_bf16(af[mi], bf[ni], acc[mi][ni], 0, 0, 0);
    }
  };

  const int nk = K >> 5;
  stage(0, 0);
  stage(1, 1);
  for (int kt = 0; kt < nk; ++kt) {
    const int cb = kt % 3;
    if (kt + 2 < nk) stage((kt + 2) % 3, kt + 2);
    wait_tile(kt, nk);          // own tile-k loads done -> barrier -> all done
    compute(cb);
    __builtin_amdgcn_sched_barrier(0);
    __builtin_amdgcn_s_barrier();   // all waves done reading buf cb before overwrite
  }

  if (vswap) {
    // acc[mi][ni] = C^T frag: d = n0+wn*64+ni*16+lhi*4+r, s = m0+wm*64+mi*16+l15
    #pragma unroll
    for (int mi = 0; mi < 4; ++mi) {
      const int sglob = m0 + wm*64 + mi*16 + l15;
      const int b2 = sglob >> 11, s = sglob & (SEQ - 1);
      #pragma unroll
      for (int ni = 0; ni < 4; ++ni) {
        #pragma unroll
        for (int r = 0; r < 4; ++r) {
          const int dglob = n0 + wn*64 + ni*16 + (lhi << 2) + r;
          const int hh = dglob >> 6, dd = dglob & 63;
          const float v = acc[mi][ni][r] + bias[dglob];
          reinterpret_cast<u16*>(Cout)[((size_t)(b2*NH + hh)*HD + dd)*SEQ + s] = f2bf(v);
        }
      }
    }
  } else {
    // C/D layout col=lane&15, row=(lane>>4)*4+reg
    #pragma unroll
    for (int mi = 0; mi < 4; ++mi) {
      const int rowb = m0 + wm*64 + mi*16 + (lhi << 2);
      #pragma unroll
      for (int ni = 0; ni < 4; ++ni) {
        const int col = n0 + wn*64 + ni*16 + l15;
        const float bb = bias[col];
        #pragma unroll
        for (int r = 0; r < 4; ++r) {
          const float v = (acc[mi][ni][r] + bb) * oscl;
          if (F32OUT)
            reinterpret_cast<float*>(Cout)[(size_t)(rowb + r) * N + col] = v;
          else
            reinterpret_cast<u16*>(Cout)[(size_t)(rowb + r) * N + col] = f2bf(v);
        }
      }
    }
  }
}

// ---------------- fused flash attention, swapped 32x32 structure ----------------
// grid (SEQ/128, NB*NH), 256 threads = 4 waves, wave w owns q rows [bx*128+32w, +32).
// Q pre-scaled by log2(e)/sqrt(d): scores in log2 domain, exp2 softmax.
// K and V^T staged in LDS, 3-deep pipeline with counted vmcnt (same protocol as GEMM).
__global__ __launch_bounds__(256, 2)
void attn32(const u16* __restrict__ Qb, const u16* __restrict__ Kb,
            const u16* __restrict__ Vt, u16* __restrict__ Ob)
{
  __shared__ u16 vt[3][64*64];   // [d][8 slots of 8 keys]
  __shared__ u16 kt[3][64*64];   // [key][8 slots of 8 d]

  const int tid = threadIdx.x;
  const int w = tid >> 6, lane = tid & 63;
  const int l31 = lane & 31, hi = lane >> 5;
  const int bh = blockIdx.y, b = bh >> 4, h = bh & 15;
  const int qrow = blockIdx.x * 128 + w * 32 + l31;

  // Q frags (B-operand: n=q=l31, k = kc*16 + hi*8 + j); issued BEFORE stages,
  // so they are strictly older than any staged tile (vmcnt counting stays valid)
  bf16x8 qf[4];
  {
    const u16* qp = Qb + (size_t)(b*SEQ + qrow) * D_MODEL + h*HD + hi*8;
    #pragma unroll
    for (int kc = 0; kc < 4; ++kc)
      qf[kc] = *reinterpret_cast<const bf16x8*>(qp + kc*16);
  }

  const u16* Vtg = Vt + (size_t)bh * HD * SEQ;            // [64 d][2048 s]
  const u16* Kg  = Kb + (size_t)(b*SEQ) * D_MODEL + h*HD; // rows [s][64 d]

  float mrun = -1e30f, lrun = 0.f;
  f32x16 o0 = {}, o1 = {};

  auto stageKV = [&](int buf, int kv0) {
    #pragma unroll
    for (int i = 0; i < 2; ++i) {
      const int c = i*256 + tid;        // chunk 0..511
      const int d = c >> 3;
      const int sl = c & 7;
      const int sg = sl ^ (d & 7);
      async_copy16((char*)vt[buf] + (size_t)(i*256 + w*64)*16,
                   (const char*)(Vtg + (size_t)d*SEQ + kv0 + sg*8));
    }
    #pragma unroll
    for (int i = 0; i < 2; ++i) {
      const int c = i*256 + tid;
      const int key = c >> 3;
      const int sl = c & 7;
      const int sg = sl ^ (key & 7);
      async_copy16((char*)kt[buf] + (size_t)(i*256 + w*64)*16,
                   (const char*)(Kg + (size_t)(kv0 + key)*D_MODEL + sg*8));
    }
  };

  const int nt = SEQ / 64;   // 32 tiles
  stageKV(0, 0);
  stageKV(1, 64);

  for (int t = 0; t < nt; ++t) {
    const int cb = t % 3;
    if (t + 2 < nt) stageKV((t + 2) % 3, (t + 2) * 64);
    wait_tile(t, nt);          // tile-t K/V in LDS for all waves

    // ---- S^T = K · Q^T from LDS: s0 = keys [t*64, +32), s1 = [+32, +64)
    f32x16 s0 = {}, s1 = {};
    {
      const char* kbp = (const char*)kt[cb];
      #pragma unroll
      for (int kc = 0; kc < 4; ++kc) {
        const int sw = (kc*2 + hi) ^ (l31 & 7);   // same for row l31 and l31+32
        bf16x8 ka0 = *reinterpret_cast<const bf16x8*>(kbp + (size_t)(l31*8 + sw)*16);
        s0 = __builtin_amdgcn_mfma_f32_32x32x16_bf16(ka0, qf[kc], s0, 0, 0, 0);
        bf16x8 ka1 = *reinterpret_cast<const bf16x8*>(kbp + (size_t)((l31+32)*8 + sw)*16);
        s1 = __builtin_amdgcn_mfma_f32_32x32x16_bf16(ka1, qf[kc], s1, 0, 0, 0);
      }
    }

    // ---- online softmax, log2 domain, defer-max
    float tmax = s0[0];
    #pragma unroll
    for (int r = 1; r < 16; ++r) tmax = fmaxf(tmax, s0[r]);
    #pragma unroll
    for (int r = 0; r < 16; ++r) tmax = fmaxf(tmax, s1[r]);
    tmax = fmaxf(tmax, __shfl_xor(tmax, 32));
    if (!__all(tmax - mrun <= DEFER_THR)) {
      const float mnew = fmaxf(mrun, tmax);
      const float a = exp2_fast(mrun - mnew);    // 0 on first tile
      lrun *= a;
      #pragma unroll
      for (int r = 0; r < 16; ++r) { o0[r] *= a; o1[r] *= a; }
      mrun = mnew;
    }
    float rs = 0.f;
    #pragma unroll
    for (int r = 0; r < 16; ++r) { s0[r] = exp2_fast(s0[r] - mrun); rs += s0[r]; }
    #pragma unroll
    for (int r = 0; r < 16; ++r) { s1[r] = exp2_fast(s1[r] - mrun); rs += s1[r]; }
    rs += __shfl_xor(rs, 32);
    lrun += rs;

    // ---- pack P: pwA[kb][a4*2+z] = keys kb*32 + 8*a4 + 4*hi + {2z, 2z+1}
    unsigned pwA[2][8];
    #pragma unroll
    for (int a4 = 0; a4 < 4; ++a4)
      #pragma unroll
      for (int zz = 0; zz < 2; ++zz) {
        pwA[0][a4*2+zz] = (unsigned)f2bf(s0[4*a4+2*zz]) | ((unsigned)f2bf(s0[4*a4+2*zz+1]) << 16);
        pwA[1][a4*2+zz] = (unsigned)f2bf(s1[4*a4+2*zz]) | ((unsigned)f2bf(s1[4*a4+2*zz+1]) << 16);
      }

    // ---- O^T += V^T · P^T over 4 key-steps of 16
    const char* vb = (const char*)vt[cb];
    #pragma unroll
    for (int ks = 0; ks < 4; ++ks) {
      const int kb = ks >> 1, sm = ks & 1;
      unsigned keep0 = hi ? pwA[kb][(2*sm+1)*2+0] : pwA[kb][(2*sm)*2+0];
      unsigned keep1 = hi ? pwA[kb][(2*sm+1)*2+1] : pwA[kb][(2*sm)*2+1];
      unsigned send0 = hi ? pwA[kb][(2*sm)*2+0]   : pwA[kb][(2*sm+1)*2+0];
      unsigned send1 = hi ? pwA[kb][(2*sm)*2+1]   : pwA[kb][(2*sm+1)*2+1];
      unsigned recv0 = (unsigned)__shfl_xor((int)send0, 32);
      unsigned recv1 = (unsigned)__shfl_xor((int)send1, 32);
      union { bf16x8 f; unsigned u[4]; } pf;
      pf.u[0] = hi ? recv0 : keep0;
      pf.u[1] = hi ? recv1 : keep1;
      pf.u[2] = hi ? keep0 : recv0;
      pf.u[3] = hi ? keep1 : recv1;

      const int slg = ks*2 + hi;
      const int sw  = slg ^ (l31 & 7);
      bf16x8 va0 = *reinterpret_cast<const bf16x8*>(vb + (size_t)(l31*8 + sw)*16);
      bf16x8 va1 = *reinterpret_cast<const bf16x8*>(vb + (size_t)((l31+32)*8 + sw)*16);

      o0 = __builtin_amdgcn_mfma_f32_32x32x16_bf16(va0, pf.f, o0, 0, 0, 0);
      o1 = __builtin_amdgcn_mfma_f32_32x32x16_bf16(va1, pf.f, o1, 0, 0, 0);
    }

    __builtin_amdgcn_sched_barrier(0);
    __builtin_amdgcn_s_barrier();   // all waves done reading buf cb before overwrite
  }

  // ---- epilogue: O^T[d][q] -> Ob[b, q, h*64 + d], d = 8*a4 + 4*hi + j (+32 for o1)
  const float inv = 1.0f / lrun;
  u16* op = Ob + (size_t)(b*SEQ + qrow) * D_MODEL + h*HD;
  #pragma unroll
  for (int a4 = 0; a4 < 4; ++a4) {
    ushort4 v0, v1;
    v0.x = f2bf(o0[4*a4+0]*inv); v0.y = f2bf(o0[4*a4+1]*inv);
    v0.z = f2bf(o0[4*a4+2]*inv); v0.w = f2bf(o0[4*a4+3]*inv);
    v1.x = f2bf(o1[4*a4+0]*inv); v1.y = f2bf(o1[4*a4+1]*inv);
    v1.z = f2bf(o1[4*a4+2]*inv); v1.w = f2bf(o1[4*a4+3]*inv);
    *reinterpret_cast<ushort4*>(op + 8*a4 + 4*hi)      = v0;
    *reinterpret_cast<ushort4*>(op + 32 + 8*a4 + 4*hi) = v1;
  }
}

// ---------------- launcher ----------------
extern "C" void kernel_launch(void* const* d_in, const int* in_sizes, int n_in,
                              void* d_out, int out_size, void* d_ws, size_t ws_size,
                              hipStream_t stream)
{
  (void)in_sizes; (void)n_in; (void)out_size;
  const float* Z  = (const float*)d_in[0];
  const float* Wq = (const float*)d_in[1];
  const float* bq = (const float*)d_in[2];
  const float* Wk = (const float*)d_in[3];
  const float* bk = (const float*)d_in[4];
  const float* Wv = (const float*)d_in[5];
  const float* bv = (const float*)d_in[6];
  const float* Wo = (const float*)d_in[7];
  const float* bo = (const float*)d_in[8];
  float* out = (float*)d_out;

  const size_t needed = (size_t)(M_TOT*D_MODEL)*2*5 + (size_t)(D_MODEL*D_MODEL)*2*4;
  if (ws_size < needed) return;

  u16* Zb  = (u16*)d_ws;
  u16* Wqb = Zb  + (size_t)M_TOT*D_MODEL;
  u16* Wkb = Wqb + (size_t)D_MODEL*D_MODEL;
  u16* Wvb = Wkb + (size_t)D_MODEL*D_MODEL;
  u16* Wob = Wvb + (size_t)D_MODEL*D_MODEL;
  u16* Qb  = Wob + (size_t)D_MODEL*D_MODEL;
  u16* Kb  = Qb  + (size_t)M_TOT*D_MODEL;
  u16* Vt  = Kb  + (size_t)M_TOT*D_MODEL;   // [b*NH+h][HD][SEQ]
  u16* Ab  = Vt  + (size_t)M_TOT*D_MODEL;

  cvt_all<<<dim3(8192), 256, 0, stream>>>(Z, Wq, Wk, Wv, Wo, Zb, Wqb, Wkb, Wvb, Wob);

  // QKV projections (Q epilogue pre-scaled by log2e/sqrt(d); V written transposed)
  dim3 gproj(D_MODEL/128, M_TOT/128, 3);
  gemm_bt<0,1><<<gproj, 256, 0, stream>>>(Zb, Wqb, Wkb, Wvb, bq, bk, bv,
                                          (void*)Qb, (void*)Kb, (void*)Vt,
                                          QSCALE, 1.0f, 1.0f,
                                          M_TOT, D_MODEL, D_MODEL);

  dim3 gattn(SEQ/128, NB*NH);
  attn32<<<gattn, 256, 0, stream>>>(Qb, Kb, Vt, Ab);

  dim3 gout(D_MODEL/128, M_TOT/128, 1);
  gemm_bt<1,0><<<gout, 256, 0, stream>>>(Ab, Wob, Wob, Wob, bo, bo, bo,
                                         (void*)out, (void*)out, (void*)out,
                                         1.0f, 1.0f, 1.0f,
                                         M_TOT, D_MODEL, D_MODEL);
}